// Round 4
// baseline (25.358 us; speedup 1.0000x reference)
//
#include <hip/hip_runtime.h>

// Problem constants (match reference setup_inputs)
#define BB 16
#define SS 256
#define NLL 66
#define VMAXX 8
#define CC 6          // CORE_IDX = [1..6]
#define CLAMP_MIN 1e-6f
#define NBLK (BB * VMAXX * CC)   // 768

// d_ws layout: [0..NBLK) double slots, then 1 u64 counter.
//
// Single kernel, single graph node, NO spinning. Each block (1 wave) computes
// one (b,v,c) cell, release-stores its partial to slot[blk], then increments
// a global counter (acq_rel, agent scope). The block that observes
// old % NBLK == NBLK-1 is the LAST block of this call: every other block's
// release (same counter address) synchronizes-with its acquire, so all 768
// fresh slots are visible. It sums them in a FIXED order (deterministic),
// normalizes, writes out.
//
// Poison/replay safety: 768 consecutive counter values contain exactly one
// value == NBLK-1 (mod NBLK), for ANY starting value — so the 0xAA-poisoned
// (or garbage) initial counter is harmless and no reset is ever needed.
__global__ __launch_bounds__(64)
void urloss_fused(const float* __restrict__ log_pa,
                  const int* __restrict__ v_label,
                  const int* __restrict__ v_l,
                  const int* __restrict__ orig_l,
                  double* __restrict__ slot,
                  unsigned long long* __restrict__ counter,
                  float* __restrict__ out) {
    const int blk = blockIdx.x;                 // b*VMAX*C + v*C + c
    const int c = blk % CC;
    const int v = (blk / CC) % VMAXX;
    const int b = blk / (CC * VMAXX);
    const int lane = threadIdx.x;

    float sum = 0.0f;
    if (v < v_l[b]) {                           // valid predicate
        const int p    = v_label[b * VMAXX + v];
        const int orig = orig_l[b];

        // element [b][p][t][1+c]
        const float* row = log_pa + ((size_t)(b * SS + p) * SS) * NLL + (1 + c);

        float vals[4];
        float m1 = 1e30f, m2 = 1e30f;
        int   idx = -1;

#pragma unroll
        for (int k = 0; k < 4; ++k) {
            const int t = lane + 64 * k;        // t < SS always
            const float lc = row[(size_t)t * NLL];   // log_core
            vals[k] = lc;
            if (t < orig) {
                const float ln = logf(fmaxf(1.0f - expf(lc), CLAMP_MIN)); // log_neg
                if (ln < m1) { m2 = m1; m1 = ln; idx = t; }
                else if (ln < m2) { m2 = ln; }
            }
        }

        // wave-reduce (m1, m2, idx); broadcast
#pragma unroll
        for (int off = 32; off >= 1; off >>= 1) {
            const float o1 = __shfl_down(m1, off);
            const float o2 = __shfl_down(m2, off);
            const int   oi = __shfl_down(idx, off);
            if (o1 < m1) { m2 = fminf(m1, o2); m1 = o1; idx = oi; }
            else         { m2 = fminf(m2, o1); }
        }
        m1  = __shfl(m1, 0);
        m2  = __shfl(m2, 0);
        idx = __shfl(idx, 0);

#pragma unroll
        for (int k = 0; k < 4; ++k) {
            const int t = lane + 64 * k;
            if (t < orig) {
                const float sel = (t == idx) ? m2 : m1;
                sum += fmaxf(vals[k] - sel, 0.0f);   // relu(log_core - min_neg)
            }
        }
#pragma unroll
        for (int off = 32; off >= 1; off >>= 1) sum += __shfl_down(sum, off);
    }

    // publish partial, then take a ticket
    unsigned long long old = 0;
    if (lane == 0) {
        __hip_atomic_store(&slot[blk], (double)sum,
                           __ATOMIC_RELEASE, __HIP_MEMORY_SCOPE_AGENT);
        old = __hip_atomic_fetch_add(counter, 1ull,
                                     __ATOMIC_ACQ_REL, __HIP_MEMORY_SCOPE_AGENT);
    }
    old = __shfl(old, 0);

    if (old % (unsigned long long)NBLK != (unsigned long long)(NBLK - 1)) return;

    // last block: all 768 fresh slots are visible. Fixed-order sum.
    double s = 0.0;
#pragma unroll
    for (int k = 0; k < NBLK / 64; ++k)
        s += __hip_atomic_load(&slot[lane + 64 * k],
                               __ATOMIC_RELAXED, __HIP_MEMORY_SCOPE_AGENT);
#pragma unroll
    for (int off = 32; off >= 1; off >>= 1)
        s += __shfl_down(s, off);

    if (lane == 0) {
        int norm = 0;
        for (int bb = 0; bb < BB; ++bb) norm += v_l[bb];
        out[0] = (float)(s / (double)norm);
    }
}

extern "C" void kernel_launch(void* const* d_in, const int* in_sizes, int n_in,
                              void* d_out, int out_size, void* d_ws, size_t ws_size,
                              hipStream_t stream) {
    const float* log_pa  = (const float*)d_in[0];
    const int*   v_label = (const int*)d_in[1];
    const int*   v_l     = (const int*)d_in[2];
    const int*   orig_l  = (const int*)d_in[3];
    double* slot = (double*)d_ws;
    unsigned long long* counter = (unsigned long long*)((char*)d_ws + NBLK * sizeof(double));

    urloss_fused<<<NBLK, 64, 0, stream>>>(log_pa, v_label, v_l, orig_l,
                                          slot, counter, (float*)d_out);
}

// Round 5
// 14.344 us; speedup vs baseline: 1.7679x; 1.7679x over previous
//
#include <hip/hip_runtime.h>

// Problem constants (match reference setup_inputs)
#define BB 16
#define SS 256
#define NLL 66          // labels per token; row stride = 264 B (8B-aligned)
#define VMAXX 8
#define CC 6            // CORE_IDX = [1..6]
#define CLAMP_MIN 1e-6f
#define NB2 32          // blocks
#define WPB 4           // waves per block; NB2*WPB = 128 = B*VMAX pairs

// d_ws layout: [0..NB2) double slots, then 1 u64 counter.
//
// Single kernel, single graph node. 32 blocks x 256 threads; each wave owns
// one (b,v) predicate pair and processes all 6 core labels. Block partials
// go through LDS, then ONE release-store + ONE acq_rel fetch_add per block
// (32 participants -> ~1us sync, vs 19us for 768 in R4). The block observing
// old % 32 == 31 is last: all other releases synchronize-with its acquire,
// so it sums the 32 fresh slots in fixed order and writes the output.
//
// Poison/replay safety: 32 consecutive counter values contain exactly one
// == 31 (mod 32) for ANY start value, so the poisoned counter needs no init;
// stale slot values are bitwise-identical to fresh ones (deterministic).
__global__ __launch_bounds__(256)
void urloss_one(const float* __restrict__ log_pa,
                const int* __restrict__ v_label,
                const int* __restrict__ v_l,
                const int* __restrict__ orig_l,
                double* __restrict__ slot,
                unsigned long long* __restrict__ counter,
                float* __restrict__ out) {
    const int tid  = threadIdx.x;
    const int lane = tid & 63;
    const int wid  = tid >> 6;
    const int blk  = blockIdx.x;
    const int pair = blk * WPB + wid;           // 0..127
    const int b = pair >> 3;
    const int v = pair & 7;

    __shared__ float wsum[WPB][CC];

    float sc[CC];
#pragma unroll
    for (int c = 0; c < CC; ++c) sc[c] = 0.0f;

    if (v < v_l[b]) {
        const int p    = v_label[b * VMAXX + v];
        const int orig = orig_l[b];
        const size_t rowbase = (size_t)(b * SS + p) * SS;

        float vals[4][CC];
        float m1[CC], m2[CC];
        int   ix[CC];
#pragma unroll
        for (int c = 0; c < CC; ++c) { m1[c] = 1e30f; m2[c] = 1e30f; ix[c] = -1; }

#pragma unroll
        for (int k = 0; k < 4; ++k) {
            const int t = lane + 64 * k;        // t < SS always
            // row of 66 floats, 8B-aligned; floats 0..7 cover labels 1..6
            const float2* r2 = (const float2*)log_pa + (rowbase + t) * (NLL / 2);
            const float2 a0 = r2[0], a1 = r2[1], a2 = r2[2], a3 = r2[3];
            vals[k][0] = a0.y;  vals[k][1] = a1.x;  vals[k][2] = a1.y;
            vals[k][3] = a2.x;  vals[k][4] = a2.y;  vals[k][5] = a3.x;
            if (t < orig) {
#pragma unroll
                for (int c = 0; c < CC; ++c) {
                    const float ln = logf(fmaxf(1.0f - expf(vals[k][c]), CLAMP_MIN));
                    if (ln < m1[c]) { m2[c] = m1[c]; m1[c] = ln; ix[c] = t; }
                    else if (ln < m2[c]) { m2[c] = ln; }
                }
            }
        }

        // wave-reduce (m1,m2,ix) per label; broadcast
#pragma unroll
        for (int off = 32; off >= 1; off >>= 1) {
#pragma unroll
            for (int c = 0; c < CC; ++c) {
                const float o1 = __shfl_down(m1[c], off);
                const float o2 = __shfl_down(m2[c], off);
                const int   oi = __shfl_down(ix[c], off);
                if (o1 < m1[c]) { m2[c] = fminf(m1[c], o2); m1[c] = o1; ix[c] = oi; }
                else            { m2[c] = fminf(m2[c], o1); }
            }
        }
#pragma unroll
        for (int c = 0; c < CC; ++c) {
            m1[c] = __shfl(m1[c], 0);
            m2[c] = __shfl(m2[c], 0);
            ix[c] = __shfl(ix[c], 0);
        }

        // pass 2: relu(log_core - min_excl_self), per-label fp32 sums
#pragma unroll
        for (int k = 0; k < 4; ++k) {
            const int t = lane + 64 * k;
            if (t < orig) {
#pragma unroll
                for (int c = 0; c < CC; ++c) {
                    const float sel = (t == ix[c]) ? m2[c] : m1[c];
                    sc[c] += fmaxf(vals[k][c] - sel, 0.0f);
                }
            }
        }
#pragma unroll
        for (int off = 32; off >= 1; off >>= 1)
#pragma unroll
            for (int c = 0; c < CC; ++c)
                sc[c] += __shfl_down(sc[c], off);
    }

    if (lane == 0)
#pragma unroll
        for (int c = 0; c < CC; ++c) wsum[wid][c] = sc[c];
    __syncthreads();
    if (wid != 0) return;

    // wave 0: publish block partial, take ticket
    unsigned long long old = 0;
    if (lane == 0) {
        double bsum = 0.0;
        for (int w = 0; w < WPB; ++w)
            for (int c = 0; c < CC; ++c)
                bsum += (double)wsum[w][c];
        __hip_atomic_store(&slot[blk], bsum,
                           __ATOMIC_RELEASE, __HIP_MEMORY_SCOPE_AGENT);
        old = __hip_atomic_fetch_add(counter, 1ull,
                                     __ATOMIC_ACQ_REL, __HIP_MEMORY_SCOPE_AGENT);
    }
    old = __shfl(old, 0);
    if (old % (unsigned long long)NB2 != (unsigned long long)(NB2 - 1)) return;

    // last block: all 32 fresh slots visible; fixed-order sum
    double d = (lane < NB2)
        ? __hip_atomic_load(&slot[lane], __ATOMIC_RELAXED, __HIP_MEMORY_SCOPE_AGENT)
        : 0.0;
#pragma unroll
    for (int off = 32; off >= 1; off >>= 1)
        d += __shfl_down(d, off);

    if (lane == 0) {
        int norm = 0;
        for (int bb = 0; bb < BB; ++bb) norm += v_l[bb];
        out[0] = (float)(d / (double)norm);
    }
}

extern "C" void kernel_launch(void* const* d_in, const int* in_sizes, int n_in,
                              void* d_out, int out_size, void* d_ws, size_t ws_size,
                              hipStream_t stream) {
    const float* log_pa  = (const float*)d_in[0];
    const int*   v_label = (const int*)d_in[1];
    const int*   v_l     = (const int*)d_in[2];
    const int*   orig_l  = (const int*)d_in[3];
    double* slot = (double*)d_ws;
    unsigned long long* counter = (unsigned long long*)((char*)d_ws + NB2 * sizeof(double));

    urloss_one<<<NB2, 256, 0, stream>>>(log_pa, v_label, v_l, orig_l,
                                        slot, counter, (float*)d_out);
}

// Round 6
// 12.797 us; speedup vs baseline: 1.9816x; 1.1209x over previous
//
#include <hip/hip_runtime.h>

// Problem constants (match reference setup_inputs)
#define BB 16
#define SS 256
#define NLL 66          // labels per token; row stride = 264 B (8B-aligned)
#define VMAXX 8
#define CC 6            // CORE_IDX = [1..6]
#define CLAMP_MIN 1e-6f
#define NPAIR (BB * VMAXX)   // 128

// d_ws layout: [0..NPAIR) double partials, one per (b,v) pair.
//
// Key algebra: f(x) = logf(fmaxf(1-expf(x), 1e-6)) is monotone NON-INCREASING
// in x (each fp32 stage is monotone), so min_t f(lc_t) == f(max_t lc_t)
// bitwise, and the self-excluded min is f(M2) iff j is the argmax else f(M1).
// Pass 1 therefore needs only fmax compares on raw lc; exp/log run twice per
// label instead of 256 times. Mask constants (+1e4 diag, +1e9 pad) can never
// win the min since orig_l >= 128 guarantees >=127 real competitors <= 0.

// Kernel 1: one wave per (b,v) pair, all 6 core labels.
__global__ __launch_bounds__(64)
void urloss_pairs(const float* __restrict__ log_pa,
                  const int* __restrict__ v_label,
                  const int* __restrict__ v_l,
                  const int* __restrict__ orig_l,
                  double* __restrict__ slot) {
    const int pair = blockIdx.x;            // b*VMAX + v
    const int b = pair >> 3;
    const int v = pair & 7;
    const int lane = threadIdx.x;

    if (v >= v_l[b]) {                      // invalid predicate: weight 0
        if (lane == 0) slot[pair] = 0.0;
        return;
    }
    const int p    = v_label[b * VMAXX + v];
    const int orig = orig_l[b];
    const size_t rowbase = (size_t)(b * SS + p) * SS;

    float vals[4][CC];
    float M1[CC], M2[CC];
    int   ix[CC];
#pragma unroll
    for (int c = 0; c < CC; ++c) { M1[c] = -1e30f; M2[c] = -1e30f; ix[c] = -1; }

#pragma unroll
    for (int k = 0; k < 4; ++k) {
        const int t = lane + 64 * k;        // t < SS always
        // row of 66 floats, 8B-aligned; float2s 0..3 cover labels 1..6
        const float2* r2 = (const float2*)log_pa + (rowbase + t) * (NLL / 2);
        const float2 a0 = r2[0], a1 = r2[1], a2 = r2[2], a3 = r2[3];
        vals[k][0] = a0.y;  vals[k][1] = a1.x;  vals[k][2] = a1.y;
        vals[k][3] = a2.x;  vals[k][4] = a2.y;  vals[k][5] = a3.x;
        if (t < orig) {
#pragma unroll
            for (int c = 0; c < CC; ++c) {
                const float lc = vals[k][c];
                if (lc > M1[c]) { M2[c] = M1[c]; M1[c] = lc; ix[c] = t; }
                else            { M2[c] = fmaxf(M2[c], lc); }
            }
        }
    }

    // wave-reduce (M1, M2, ix) per label; broadcast
#pragma unroll
    for (int off = 32; off >= 1; off >>= 1) {
#pragma unroll
        for (int c = 0; c < CC; ++c) {
            const float o1 = __shfl_down(M1[c], off);
            const float o2 = __shfl_down(M2[c], off);
            const int   oi = __shfl_down(ix[c], off);
            if (o1 > M1[c]) { M2[c] = fmaxf(M1[c], o2); M1[c] = o1; ix[c] = oi; }
            else            { M2[c] = fmaxf(M2[c], o1); }
        }
    }
#pragma unroll
    for (int c = 0; c < CC; ++c) {
        M1[c] = __shfl(M1[c], 0);
        M2[c] = __shfl(M2[c], 0);
        ix[c] = __shfl(ix[c], 0);
    }

    // evaluate f at the two winners per label (identical fp32 ops to ref)
    float mn1[CC], mn2[CC];
#pragma unroll
    for (int c = 0; c < CC; ++c) {
        mn1[c] = logf(fmaxf(1.0f - expf(M1[c]), CLAMP_MIN));
        mn2[c] = logf(fmaxf(1.0f - expf(M2[c]), CLAMP_MIN));
    }

    // pass 2: relu(log_core - min_excl_self), per-label fp32 sums
    float sc[CC];
#pragma unroll
    for (int c = 0; c < CC; ++c) sc[c] = 0.0f;
#pragma unroll
    for (int k = 0; k < 4; ++k) {
        const int t = lane + 64 * k;
        if (t < orig) {
#pragma unroll
            for (int c = 0; c < CC; ++c) {
                const float sel = (t == ix[c]) ? mn2[c] : mn1[c];
                sc[c] += fmaxf(vals[k][c] - sel, 0.0f);
            }
        }
    }
#pragma unroll
    for (int off = 32; off >= 1; off >>= 1)
#pragma unroll
        for (int c = 0; c < CC; ++c)
            sc[c] += __shfl_down(sc[c], off);

    if (lane == 0) {
        double d = 0.0;
#pragma unroll
        for (int c = 0; c < CC; ++c) d += (double)sc[c];
        slot[pair] = d;
    }
}

// Kernel 2: single wave; reduce 128 doubles + normalize.
__global__ __launch_bounds__(64)
void urloss_reduce(const double* __restrict__ slot,
                   const int* __restrict__ v_l,
                   float* __restrict__ out) {
    const int lane = threadIdx.x;
    double s = slot[lane] + slot[lane + 64];
    int nv = (lane < BB) ? v_l[lane] : 0;
#pragma unroll
    for (int off = 32; off >= 1; off >>= 1) {
        s  += __shfl_down(s, off);
        nv += __shfl_down(nv, off);
    }
    if (lane == 0) out[0] = (float)(s / (double)nv);
}

extern "C" void kernel_launch(void* const* d_in, const int* in_sizes, int n_in,
                              void* d_out, int out_size, void* d_ws, size_t ws_size,
                              hipStream_t stream) {
    const float* log_pa  = (const float*)d_in[0];
    const int*   v_label = (const int*)d_in[1];
    const int*   v_l     = (const int*)d_in[2];
    const int*   orig_l  = (const int*)d_in[3];
    double* slot = (double*)d_ws;

    urloss_pairs<<<NPAIR, 64, 0, stream>>>(log_pa, v_label, v_l, orig_l, slot);
    urloss_reduce<<<1, 64, 0, stream>>>(slot, v_l, (float*)d_out);
}

// Round 7
// 12.627 us; speedup vs baseline: 2.0082x; 1.0134x over previous
//
#include <hip/hip_runtime.h>

// Problem constants (match reference setup_inputs)
#define BB 16
#define SS 256
#define NLL 66          // labels per token; row stride = 264 B (8B-aligned)
#define VMAXX 8
#define CC 6            // CORE_IDX = [1..6]
#define CLAMP_MIN 1e-6f
#define NB2 32          // blocks
#define WPB 4           // waves per block; NB2*WPB = 128 = B*VMAX pairs

// d_ws layout: [0..NB2) double slots, then 1 u64 counter.
//
// Single node. 32 blocks x 4 waves; each wave owns one (b,v) pair, all 6
// core labels. Monotonicity: f(x)=logf(fmaxf(1-expf(x),1e-6)) is monotone
// non-increasing in fp32, so min_t f(lc_t) = f(max_t lc_t) bitwise and the
// self-excluded min is f(M2) iff t==argmax else f(M1) — pass 1 is pure fmax,
// exp/log runs twice per label. Masks (+1e4/+1e9) can't win: orig_l >= 128.
//
// Fan-in: block partial via LDS -> ONE release slot-store + ONE acq_rel
// ticket per block. The block seeing old % 32 == 31 is last (all releases
// synchronize-with its acquire); it sums 32 fresh slots in fixed order.
// Replay/poison-safe: slots are idempotent (deterministic rewrite); any 32
// consecutive ticket values contain exactly one == 31 (mod 32), so the
// poisoned counter needs no init.
__global__ __launch_bounds__(256)
void urloss_one(const float* __restrict__ log_pa,
                const int* __restrict__ v_label,
                const int* __restrict__ v_l,
                const int* __restrict__ orig_l,
                double* __restrict__ slot,
                unsigned long long* __restrict__ counter,
                float* __restrict__ out) {
    const int tid  = threadIdx.x;
    const int lane = tid & 63;
    const int wid  = tid >> 6;
    const int blk  = blockIdx.x;
    const int pair = blk * WPB + wid;       // 0..127
    const int b = pair >> 3;
    const int v = pair & 7;

    __shared__ double wsum[WPB];

    double mysum = 0.0;
    if (v < v_l[b]) {
        const int p    = v_label[b * VMAXX + v];
        const int orig = orig_l[b];
        const size_t rowbase = (size_t)(b * SS + p) * SS;

        float vals[4][CC];
        float M1[CC], M2[CC];
        int   ix[CC];
#pragma unroll
        for (int c = 0; c < CC; ++c) { M1[c] = -1e30f; M2[c] = -1e30f; ix[c] = -1; }

#pragma unroll
        for (int k = 0; k < 4; ++k) {
            const int t = lane + 64 * k;    // t < SS always
            // row of 66 floats, 8B-aligned; float2s 0..3 cover labels 1..6
            const float2* r2 = (const float2*)log_pa + (rowbase + t) * (NLL / 2);
            const float2 a0 = r2[0], a1 = r2[1], a2 = r2[2], a3 = r2[3];
            vals[k][0] = a0.y;  vals[k][1] = a1.x;  vals[k][2] = a1.y;
            vals[k][3] = a2.x;  vals[k][4] = a2.y;  vals[k][5] = a3.x;
            if (t < orig) {
#pragma unroll
                for (int c = 0; c < CC; ++c) {
                    const float lc = vals[k][c];
                    if (lc > M1[c]) { M2[c] = M1[c]; M1[c] = lc; ix[c] = t; }
                    else            { M2[c] = fmaxf(M2[c], lc); }
                }
            }
        }

        // wave-reduce (M1, M2, ix) per label; broadcast
#pragma unroll
        for (int off = 32; off >= 1; off >>= 1) {
#pragma unroll
            for (int c = 0; c < CC; ++c) {
                const float o1 = __shfl_down(M1[c], off);
                const float o2 = __shfl_down(M2[c], off);
                const int   oi = __shfl_down(ix[c], off);
                if (o1 > M1[c]) { M2[c] = fmaxf(M1[c], o2); M1[c] = o1; ix[c] = oi; }
                else            { M2[c] = fmaxf(M2[c], o1); }
            }
        }
#pragma unroll
        for (int c = 0; c < CC; ++c) {
            M1[c] = __shfl(M1[c], 0);
            M2[c] = __shfl(M2[c], 0);
            ix[c] = __shfl(ix[c], 0);
        }

        // f at the two winners per label (identical fp32 ops to reference)
        float mn1[CC], mn2[CC];
#pragma unroll
        for (int c = 0; c < CC; ++c) {
            mn1[c] = logf(fmaxf(1.0f - expf(M1[c]), CLAMP_MIN));
            mn2[c] = logf(fmaxf(1.0f - expf(M2[c]), CLAMP_MIN));
        }

        // pass 2: relu(log_core - min_excl_self), per-label fp32 sums
        float sc[CC];
#pragma unroll
        for (int c = 0; c < CC; ++c) sc[c] = 0.0f;
#pragma unroll
        for (int k = 0; k < 4; ++k) {
            const int t = lane + 64 * k;
            if (t < orig) {
#pragma unroll
                for (int c = 0; c < CC; ++c) {
                    const float sel = (t == ix[c]) ? mn2[c] : mn1[c];
                    sc[c] += fmaxf(vals[k][c] - sel, 0.0f);
                }
            }
        }
#pragma unroll
        for (int off = 32; off >= 1; off >>= 1)
#pragma unroll
            for (int c = 0; c < CC; ++c)
                sc[c] += __shfl_down(sc[c], off);

        if (lane == 0)
#pragma unroll
            for (int c = 0; c < CC; ++c) mysum += (double)sc[c];
    }

    if (lane == 0) wsum[wid] = mysum;
    __syncthreads();
    if (wid != 0) return;

    // wave 0: publish block partial, take ticket
    unsigned long long old = 0;
    if (lane == 0) {
        const double bsum = wsum[0] + wsum[1] + wsum[2] + wsum[3];
        __hip_atomic_store(&slot[blk], bsum,
                           __ATOMIC_RELEASE, __HIP_MEMORY_SCOPE_AGENT);
        old = __hip_atomic_fetch_add(counter, 1ull,
                                     __ATOMIC_ACQ_REL, __HIP_MEMORY_SCOPE_AGENT);
    }
    old = __shfl(old, 0);
    if (old % (unsigned long long)NB2 != (unsigned long long)(NB2 - 1)) return;

    // last block: all 32 fresh slots visible; fixed-order sum in one wave
    double d = (lane < NB2)
        ? __hip_atomic_load(&slot[lane], __ATOMIC_RELAXED, __HIP_MEMORY_SCOPE_AGENT)
        : 0.0;
#pragma unroll
    for (int off = 32; off >= 1; off >>= 1)
        d += __shfl_down(d, off);

    if (lane == 0) {
        int norm = 0;
        for (int bb = 0; bb < BB; ++bb) norm += v_l[bb];
        out[0] = (float)(d / (double)norm);
    }
}

extern "C" void kernel_launch(void* const* d_in, const int* in_sizes, int n_in,
                              void* d_out, int out_size, void* d_ws, size_t ws_size,
                              hipStream_t stream) {
    const float* log_pa  = (const float*)d_in[0];
    const int*   v_label = (const int*)d_in[1];
    const int*   v_l     = (const int*)d_in[2];
    const int*   orig_l  = (const int*)d_in[3];
    double* slot = (double*)d_ws;
    unsigned long long* counter = (unsigned long long*)((char*)d_ws + NB2 * sizeof(double));

    urloss_one<<<NB2, 256, 0, stream>>>(log_pa, v_label, v_l, orig_l,
                                        slot, counter, (float*)d_out);
}